// Round 1
// baseline (1294.276 us; speedup 1.0000x reference)
//
#include <hip/hip_runtime.h>

// SpecialSpmmFinal: out[n1, f] = sum over edges e with src[e]==n1 of edge_w[e, f]
// N1=100000, E=3.2M, F=32 (derived host-side from sizes; F==32 specialized).

__global__ __launch_bounds__(256) void zero_out_kernel(float* __restrict__ out, int n) {
    int i = blockIdx.x * 256 + threadIdx.x;
    if (i < n) out[i] = 0.0f;
}

// One thread per (edge, 4-feature quad). F == 32 specialization: 8 quads/edge.
__global__ __launch_bounds__(256) void scatter_add_f32x4_kernel(
    const int* __restrict__ src,
    const float4* __restrict__ w,      // edge_w viewed as [E, 8] float4
    float* __restrict__ out,           // [N1, 32]
    int total_quads)                   // E * 8
{
    int tid = blockIdx.x * 256 + threadIdx.x;
    if (tid >= total_quads) return;
    int e  = tid >> 3;     // edge index
    int fq = tid & 7;      // which float4 within the 32-feature row
    float4 v = w[tid];     // fully coalesced: 16B/lane, contiguous across lanes
    int s = src[e];        // 8 lanes share this address -> cache broadcast
    float* o = out + (long long)s * 32 + fq * 4;
    unsafeAtomicAdd(o + 0, v.x);   // global_atomic_add_f32 (HW atomic, no CAS loop)
    unsafeAtomicAdd(o + 1, v.y);
    unsafeAtomicAdd(o + 2, v.z);
    unsafeAtomicAdd(o + 3, v.w);
}

// Generic fallback for F != 32: one thread per (edge, feature).
__global__ __launch_bounds__(256) void scatter_add_generic_kernel(
    const int* __restrict__ src,
    const float* __restrict__ w,
    float* __restrict__ out,
    long long total, int F)
{
    long long tid = (long long)blockIdx.x * 256 + threadIdx.x;
    if (tid >= total) return;
    int e = (int)(tid / F);
    int f = (int)(tid % F);
    int s = src[e];
    unsafeAtomicAdd(out + (long long)s * F + f, w[tid]);
}

extern "C" void kernel_launch(void* const* d_in, const int* in_sizes, int n_in,
                              void* d_out, int out_size, void* d_ws, size_t ws_size,
                              hipStream_t stream) {
    const int* edge   = (const int*)d_in[0];     // [2, E] int32; edge[0] = src
    const float* w    = (const float*)d_in[1];   // [E, F] float32
    float* out        = (float*)d_out;           // [N1, F] float32

    const int E = in_sizes[0] / 2;
    const int F = in_sizes[1] / E;

    // 1) zero the output (harness poisons d_out with 0xAA; we must re-zero every call)
    {
        int blocks = (out_size + 255) / 256;
        zero_out_kernel<<<blocks, 256, 0, stream>>>(out, out_size);
    }

    // 2) scatter-add
    const int* src = edge;  // first E entries = edge[0]
    if (F == 32) {
        int total_quads = E * 8;
        int blocks = (total_quads + 255) / 256;
        scatter_add_f32x4_kernel<<<blocks, 256, 0, stream>>>(
            src, (const float4*)w, out, total_quads);
    } else {
        long long total = (long long)E * F;
        int blocks = (int)((total + 255) / 256);
        scatter_add_generic_kernel<<<blocks, 256, 0, stream>>>(
            src, w, out, total, F);
    }
}

// Round 2
// 739.146 us; speedup vs baseline: 1.7510x; 1.7510x over previous
//
#include <hip/hip_runtime.h>

// SpecialSpmmFinal: out[n1, f] = sum over edges e with src[e]==n1 of edge_w[e, f]
// N1=100000, E=3.2M, F=32 (F==32 specialized CSR-gather path; atomic fallback otherwise).
//
// Strategy: build CSR in d_ws (hist -> scan -> fill perm), then gather-sum per node.
// Eliminates 102.4M fp32 memory-side atomics (the R1 bottleneck: 80 G atomics/s,
// 1.6 GB atomic write traffic) in favor of 6.4M int atomics on L2-resident counters.

// ---------- CSR build ----------

__global__ __launch_bounds__(256) void zero_counts_kernel(int* __restrict__ counts, int n) {
    int i = blockIdx.x * 256 + threadIdx.x;
    if (i < n) counts[i] = 0;
}

__global__ __launch_bounds__(256) void hist_kernel(const int* __restrict__ src,
                                                   int* __restrict__ counts, int E) {
    int stride = gridDim.x * 256;
    for (int i = blockIdx.x * 256 + threadIdx.x; i < E; i += stride)
        atomicAdd(&counts[src[i]], 1);
}

// Single-block exclusive scan: counts (aliased with cursors) -> offsets, cursors.
// Each thread owns a contiguous chunk; Hillis-Steele scan of the 1024 partials in LDS.
__global__ __launch_bounds__(1024) void scan_kernel(const int* __restrict__ counts,
                                                    int* __restrict__ offsets,
                                                    int* __restrict__ cursors,
                                                    int N1, int E) {
    __shared__ int s[1024];
    int t = threadIdx.x;
    int C = (N1 + 1023) >> 10;
    int beg = t * C;
    int end = beg + C; if (end > N1) end = N1;
    int sum = 0;
    for (int i = beg; i < end; ++i) sum += counts[i];
    s[t] = sum;
    __syncthreads();
    for (int off = 1; off < 1024; off <<= 1) {
        int v = (t >= off) ? s[t - off] : 0;
        __syncthreads();
        s[t] += v;
        __syncthreads();
    }
    int run = s[t] - sum;  // exclusive prefix for this thread's chunk
    for (int i = beg; i < end; ++i) {
        int c = counts[i];       // NB: counts aliases cursors; read before write, per-thread serial
        offsets[i] = run;
        cursors[i] = run;
        run += c;
    }
    if (t == 0) offsets[N1] = E;
}

__global__ __launch_bounds__(256) void fill_perm_kernel(const int* __restrict__ src,
                                                        int* __restrict__ cursors,
                                                        int* __restrict__ perm, int E) {
    int stride = gridDim.x * 256;
    for (int i = blockIdx.x * 256 + threadIdx.x; i < E; i += stride) {
        int s = src[i];
        int p = atomicAdd(&cursors[s], 1);
        perm[p] = i;
    }
}

// ---------- gather-sum (F == 32) ----------
// 8 lanes per node; lane `sub` owns float4 #sub of the 32-float row.
// perm reads are sequential (L1-resident); edge_w row reads are 128B-granular gathers.
__global__ __launch_bounds__(256) void gather_sum_kernel(const int* __restrict__ offsets,
                                                         const int* __restrict__ perm,
                                                         const float4* __restrict__ w4,
                                                         float4* __restrict__ out4,
                                                         int N1) {
    int node = blockIdx.x * 32 + (threadIdx.x >> 3);
    if (node >= N1) return;
    int sub = threadIdx.x & 7;
    int beg = offsets[node];
    int end = offsets[node + 1];
    float4 acc; acc.x = 0.f; acc.y = 0.f; acc.z = 0.f; acc.w = 0.f;
    int i = beg;
    // unroll-by-4: 4 independent row loads in flight per iteration
    for (; i + 4 <= end; i += 4) {
        int e0 = perm[i], e1 = perm[i + 1], e2 = perm[i + 2], e3 = perm[i + 3];
        float4 a = w4[(long long)e0 * 8 + sub];
        float4 b = w4[(long long)e1 * 8 + sub];
        float4 c = w4[(long long)e2 * 8 + sub];
        float4 d = w4[(long long)e3 * 8 + sub];
        acc.x += (a.x + b.x) + (c.x + d.x);
        acc.y += (a.y + b.y) + (c.y + d.y);
        acc.z += (a.z + b.z) + (c.z + d.z);
        acc.w += (a.w + b.w) + (c.w + d.w);
    }
    for (; i < end; ++i) {
        float4 a = w4[(long long)perm[i] * 8 + sub];
        acc.x += a.x; acc.y += a.y; acc.z += a.z; acc.w += a.w;
    }
    out4[(long long)node * 8 + sub] = acc;
}

// ---------- fallback (F != 32 or ws too small): R1 atomic path ----------

__global__ __launch_bounds__(256) void zero_out_kernel(float* __restrict__ out, int n) {
    int i = blockIdx.x * 256 + threadIdx.x;
    if (i < n) out[i] = 0.0f;
}

__global__ __launch_bounds__(256) void scatter_add_generic_kernel(
    const int* __restrict__ src,
    const float* __restrict__ w,
    float* __restrict__ out,
    long long total, int F)
{
    long long tid = (long long)blockIdx.x * 256 + threadIdx.x;
    if (tid >= total) return;
    int e = (int)(tid / F);
    int f = (int)(tid % F);
    int s = src[e];
    unsafeAtomicAdd(out + (long long)s * F + f, w[tid]);
}

extern "C" void kernel_launch(void* const* d_in, const int* in_sizes, int n_in,
                              void* d_out, int out_size, void* d_ws, size_t ws_size,
                              hipStream_t stream) {
    const int* edge = (const int*)d_in[0];    // [2, E]; first E = src
    const float* w  = (const float*)d_in[1];  // [E, F]
    float* out      = (float*)d_out;          // [N1, F]

    const int E  = in_sizes[0] / 2;
    const int F  = in_sizes[1] / E;
    const int N1 = out_size / F;
    const int* src = edge;

    // ws layout: offsets[N1+1] | cursors[N1] | perm[E]
    size_t need = (size_t)(N1 + 1 + N1 + E) * sizeof(int);

    if (F == 32 && ws_size >= need) {
        int* offsets = (int*)d_ws;
        int* cursors = offsets + (N1 + 1);
        int* perm    = cursors + N1;

        zero_counts_kernel<<<(N1 + 255) / 256, 256, 0, stream>>>(cursors, N1);
        hist_kernel<<<2048, 256, 0, stream>>>(src, cursors, E);
        scan_kernel<<<1, 1024, 0, stream>>>(cursors, offsets, cursors, N1, E);
        fill_perm_kernel<<<2048, 256, 0, stream>>>(src, cursors, perm, E);
        gather_sum_kernel<<<(N1 + 31) / 32, 256, 0, stream>>>(
            offsets, perm, (const float4*)w, (float4*)out, N1);
    } else {
        zero_out_kernel<<<(out_size + 255) / 256, 256, 0, stream>>>(out, out_size);
        long long total = (long long)E * F;
        scatter_add_generic_kernel<<<(int)((total + 255) / 256), 256, 0, stream>>>(
            src, w, out, total, F);
    }
}

// Round 3
// 438.238 us; speedup vs baseline: 2.9534x; 1.6866x over previous
//
#include <hip/hip_runtime.h>

// SpecialSpmmFinal: out[n1, f] = sum over edges e with src[e]==n1 of edge_w[e, f]
// N1=100000, E=3.2M, F=32.
//
// R3: CSR build reworked.
//  - hist_rank: rank[e] = atomicAdd(counts[src[e]]) -- rank write is coalesced.
//  - scan: in-place exclusive scan counts -> offsets (single block).
//  - fill:  perm[offsets[s]+rank[e]] = e, ATOMIC-FREE, partitioned into 8 node
//    ranges (range = blockIdx & 7 -> XCD-local 1.6MB perm window) so scattered
//    4B stores fill whole lines within one XCD's L2 (R2 showed 61B/store HBM
//    write amplification from cross-XCD partial-line writes: 195MB for 12.8MB).
//  - gather_sum: unchanged (8 lanes/node, float4, unroll-4).

#define NR 8  // node ranges == XCDs

__global__ __launch_bounds__(256) void zero_kernel(int* __restrict__ p, int n) {
    int i = blockIdx.x * 256 + threadIdx.x;
    if (i < n) p[i] = 0;
}

// ---- Path A: histogram + per-edge rank (coalesced rank write) ----
__global__ __launch_bounds__(256) void hist_rank_kernel(const int* __restrict__ src,
                                                        int* __restrict__ counts,
                                                        int* __restrict__ rank, int E) {
    int e = blockIdx.x * 256 + threadIdx.x;
    if (e < E) rank[e] = atomicAdd(&counts[src[e]], 1);
}

// ---- Path B histogram (no rank) ----
__global__ __launch_bounds__(256) void hist_kernel(const int* __restrict__ src,
                                                   int* __restrict__ counts, int E) {
    int stride = gridDim.x * 256;
    for (int i = blockIdx.x * 256 + threadIdx.x; i < E; i += stride)
        atomicAdd(&counts[src[i]], 1);
}

// In-place exclusive scan: cnt_off[0..N1) counts -> offsets; cnt_off[N1] = E.
// Optionally mirrors the running offsets into cursors (path B).
__global__ __launch_bounds__(1024) void scan_kernel(int* __restrict__ cnt_off,
                                                    int* __restrict__ cursors,
                                                    int N1, int E, int want_cursors) {
    __shared__ int s[1024];
    int t = threadIdx.x;
    int C = (N1 + 1023) >> 10;
    int beg = t * C;
    int end = beg + C; if (end > N1) end = N1; if (beg > N1) beg = N1;
    int sum = 0;
    for (int i = beg; i < end; ++i) sum += cnt_off[i];
    s[t] = sum;
    __syncthreads();
    for (int off = 1; off < 1024; off <<= 1) {
        int v = (t >= off) ? s[t - off] : 0;
        __syncthreads();
        s[t] += v;
        __syncthreads();
    }
    int run = s[t] - sum;  // exclusive prefix of this chunk
    for (int i = beg; i < end; ++i) {
        int c = cnt_off[i];          // read count before overwriting (same thread)
        cnt_off[i] = run;
        if (want_cursors) cursors[i] = run;
        run += c;
    }
    if (t == 0) cnt_off[N1] = E;
}

// ---- Path A fill: atomic-free, node-range partitioned ----
__global__ __launch_bounds__(256) void fill_rank_kernel(const int* __restrict__ src,
                                                        const int* __restrict__ offsets,
                                                        const int* __restrict__ rank,
                                                        int* __restrict__ perm,
                                                        int E, int N1, int rsize) {
    int range = blockIdx.x & (NR - 1);        // consecutive blocks -> different XCDs
    int lo = range * rsize;
    int hi = lo + rsize; if (hi > N1) hi = N1;
    int stride = (gridDim.x >> 3) * 256;
    for (int e = (blockIdx.x >> 3) * 256 + threadIdx.x; e < E; e += stride) {
        int s = src[e];
        if (s >= lo && s < hi)
            perm[offsets[s] + rank[e]] = e;   // scattered 4B store, XCD-local window
    }
}

// ---- Path B fill: cursor atomics, node-range partitioned ----
__global__ __launch_bounds__(256) void fill_atomic_kernel(const int* __restrict__ src,
                                                          int* __restrict__ cursors,
                                                          int* __restrict__ perm,
                                                          int E, int N1, int rsize) {
    int range = blockIdx.x & (NR - 1);
    int lo = range * rsize;
    int hi = lo + rsize; if (hi > N1) hi = N1;
    int stride = (gridDim.x >> 3) * 256;
    for (int e = (blockIdx.x >> 3) * 256 + threadIdx.x; e < E; e += stride) {
        int s = src[e];
        if (s >= lo && s < hi) {
            int p = atomicAdd(&cursors[s], 1);
            perm[p] = e;
        }
    }
}

// ---- gather-sum (F == 32): 8 lanes per node, lane owns one float4 quad ----
__global__ __launch_bounds__(256) void gather_sum_kernel(const int* __restrict__ offsets,
                                                         const int* __restrict__ perm,
                                                         const float4* __restrict__ w4,
                                                         float4* __restrict__ out4,
                                                         int N1) {
    int node = blockIdx.x * 32 + (threadIdx.x >> 3);
    if (node >= N1) return;
    int sub = threadIdx.x & 7;
    int beg = offsets[node];
    int end = offsets[node + 1];
    float4 acc; acc.x = 0.f; acc.y = 0.f; acc.z = 0.f; acc.w = 0.f;
    int i = beg;
    for (; i + 4 <= end; i += 4) {
        int e0 = perm[i], e1 = perm[i + 1], e2 = perm[i + 2], e3 = perm[i + 3];
        float4 a = w4[(long long)e0 * 8 + sub];
        float4 b = w4[(long long)e1 * 8 + sub];
        float4 c = w4[(long long)e2 * 8 + sub];
        float4 d = w4[(long long)e3 * 8 + sub];
        acc.x += (a.x + b.x) + (c.x + d.x);
        acc.y += (a.y + b.y) + (c.y + d.y);
        acc.z += (a.z + b.z) + (c.z + d.z);
        acc.w += (a.w + b.w) + (c.w + d.w);
    }
    for (; i < end; ++i) {
        float4 a = w4[(long long)perm[i] * 8 + sub];
        acc.x += a.x; acc.y += a.y; acc.z += a.z; acc.w += a.w;
    }
    out4[(long long)node * 8 + sub] = acc;
}

// ---- Path C fallback: direct atomic scatter ----
__global__ __launch_bounds__(256) void zero_out_kernel(float* __restrict__ out, int n) {
    int i = blockIdx.x * 256 + threadIdx.x;
    if (i < n) out[i] = 0.0f;
}

__global__ __launch_bounds__(256) void scatter_add_generic_kernel(
    const int* __restrict__ src, const float* __restrict__ w,
    float* __restrict__ out, long long total, int F) {
    long long tid = (long long)blockIdx.x * 256 + threadIdx.x;
    if (tid >= total) return;
    int e = (int)(tid / F);
    int f = (int)(tid % F);
    unsafeAtomicAdd(out + (long long)src[e] * F + f, w[tid]);
}

extern "C" void kernel_launch(void* const* d_in, const int* in_sizes, int n_in,
                              void* d_out, int out_size, void* d_ws, size_t ws_size,
                              hipStream_t stream) {
    const int* edge = (const int*)d_in[0];    // [2, E]; first E = src
    const float* w  = (const float*)d_in[1];  // [E, F]
    float* out      = (float*)d_out;          // [N1, F]

    const int E  = in_sizes[0] / 2;
    const int F  = in_sizes[1] / E;
    const int N1 = out_size / F;
    const int* src = edge;
    const int rsize = (N1 + NR - 1) / NR;

    // Path A layout: cnt_off[N1+1] | rank[E] | perm[E]
    size_t need_a = (size_t)(N1 + 1 + 2LL * E) * sizeof(int);
    // Path B layout: cnt_off[N1+1] | cursors[N1] | perm[E]
    size_t need_b = (size_t)(N1 + 1 + N1 + E) * sizeof(int);

    if (F == 32 && ws_size >= need_a) {
        int* cnt_off = (int*)d_ws;            // counts, then offsets (in-place scan)
        int* rank    = cnt_off + (N1 + 1);
        int* perm    = rank + E;

        zero_kernel<<<(N1 + 255) / 256, 256, 0, stream>>>(cnt_off, N1);
        hist_rank_kernel<<<(E + 255) / 256, 256, 0, stream>>>(src, cnt_off, rank, E);
        scan_kernel<<<1, 1024, 0, stream>>>(cnt_off, nullptr, N1, E, 0);
        fill_rank_kernel<<<NR * 256, 256, 0, stream>>>(src, cnt_off, rank, perm, E, N1, rsize);
        gather_sum_kernel<<<(N1 + 31) / 32, 256, 0, stream>>>(
            cnt_off, perm, (const float4*)w, (float4*)out, N1);
    } else if (F == 32 && ws_size >= need_b) {
        int* cnt_off = (int*)d_ws;
        int* cursors = cnt_off + (N1 + 1);
        int* perm    = cursors + N1;

        zero_kernel<<<(N1 + 255) / 256, 256, 0, stream>>>(cnt_off, N1);
        hist_kernel<<<2048, 256, 0, stream>>>(src, cnt_off, E);
        scan_kernel<<<1, 1024, 0, stream>>>(cnt_off, cursors, N1, E, 1);
        fill_atomic_kernel<<<NR * 256, 256, 0, stream>>>(src, cursors, perm, E, N1, rsize);
        gather_sum_kernel<<<(N1 + 31) / 32, 256, 0, stream>>>(
            cnt_off, perm, (const float4*)w, (float4*)out, N1);
    } else {
        zero_out_kernel<<<(out_size + 255) / 256, 256, 0, stream>>>(out, out_size);
        long long total = (long long)E * F;
        scatter_add_generic_kernel<<<(int)((total + 255) / 256), 256, 0, stream>>>(
            src, w, out, total, F);
    }
}

// Round 4
// 232.593 us; speedup vs baseline: 5.5645x; 1.8841x over previous
//
#include <hip/hip_runtime.h>

// SpecialSpmmFinal: out[n1, f] = sum over edges e with src[e]==n1 of edge_w[e, f]
// N1=100000, E=3.2M, F=32.
//
// R4 pipeline (F==32):
//   1. zero counts + ovf counter (400KB)
//   2. hist_fill: fused histogram + padded-slot fill, XCD-range-partitioned.
//      rank = atomicAdd(&count[s]) and perm_pad[s*64+rank] = e in one kernel;
//      range = blockIdx&7 keeps both the atomic and the 4B scatter inside a
//      3.2MB XCD-local window (<4MB L2)  -> no cross-XCD partial-line writeback
//      (R2 measured 61B HBM write per 4B store without this). Costs 8x re-read
//      of src (102MB, L3-resident). Eliminates scan + separate fill + rank arr.
//   3. gather_sum: 8 lanes/node, float4, unroll-8; offsets computed (node*64),
//      one count load per group. Writes every out element (no out zeroing).
//   4. overflow_scatter: atomic-add for edges whose node degree > PAD (p~1e-9
//      for this input; correctness guard only).

#define NR   8    // node ranges == XCDs
#define PAD  64   // padded slots per node (mean degree 32, max ~59 for E/N1 multinomial)
#define OVF_CAP 8192

__global__ __launch_bounds__(256) void zero_kernel(int* __restrict__ p, int n) {
    int i = blockIdx.x * 256 + threadIdx.x;
    if (i < n) p[i] = 0;
}

// Fused histogram + padded fill, node-range partitioned.
__global__ __launch_bounds__(256) void hist_fill_kernel(const int* __restrict__ src,
                                                        int* __restrict__ counts,
                                                        int* __restrict__ perm_pad,
                                                        int* __restrict__ ovf,      // [0]=count, [1..]=edge ids
                                                        int E, int N1, int rsize) {
    int range = blockIdx.x & (NR - 1);       // consecutive blocks -> different XCDs
    int lo = range * rsize;
    int hi = lo + rsize; if (hi > N1) hi = N1;
    int bid = blockIdx.x >> 3;               // block index within this range
    int nblk = gridDim.x >> 3;               // blocks per range
    int stride = nblk * 256 * 4;
    for (int e0 = (bid * 256 + threadIdx.x) * 4; e0 < E; e0 += stride) {
        if (e0 + 4 <= E) {
            int4 s4 = *reinterpret_cast<const int4*>(src + e0);
            int ss[4] = {s4.x, s4.y, s4.z, s4.w};
            #pragma unroll
            for (int k = 0; k < 4; ++k) {
                int s = ss[k];
                if (s >= lo && s < hi) {
                    int r = atomicAdd(&counts[s], 1);
                    if (r < PAD) perm_pad[s * PAD + r] = e0 + k;
                    else {
                        int p = atomicAdd(&ovf[0], 1);
                        if (p < OVF_CAP) ovf[1 + p] = e0 + k;
                    }
                }
            }
        } else {
            for (int e = e0; e < E; ++e) {
                int s = src[e];
                if (s >= lo && s < hi) {
                    int r = atomicAdd(&counts[s], 1);
                    if (r < PAD) perm_pad[s * PAD + r] = e;
                    else {
                        int p = atomicAdd(&ovf[0], 1);
                        if (p < OVF_CAP) ovf[1 + p] = e;
                    }
                }
            }
        }
    }
}

// gather-sum (F == 32): 8 lanes per node, lane owns one float4 quad of the row.
__global__ __launch_bounds__(256) void gather_sum_kernel(const int* __restrict__ counts,
                                                         const int* __restrict__ perm_pad,
                                                         const float4* __restrict__ w4,
                                                         float4* __restrict__ out4,
                                                         int N1) {
    int node = blockIdx.x * 32 + (threadIdx.x >> 3);
    if (node >= N1) return;
    int sub = threadIdx.x & 7;
    int cnt = counts[node]; if (cnt > PAD) cnt = PAD;
    const int* pp = perm_pad + node * PAD;
    float4 acc; acc.x = 0.f; acc.y = 0.f; acc.z = 0.f; acc.w = 0.f;
    int i = 0;
    for (; i + 8 <= cnt; i += 8) {       // 8 independent 128B row reads in flight
        float4 a0 = w4[(long long)pp[i + 0] * 8 + sub];
        float4 a1 = w4[(long long)pp[i + 1] * 8 + sub];
        float4 a2 = w4[(long long)pp[i + 2] * 8 + sub];
        float4 a3 = w4[(long long)pp[i + 3] * 8 + sub];
        float4 a4 = w4[(long long)pp[i + 4] * 8 + sub];
        float4 a5 = w4[(long long)pp[i + 5] * 8 + sub];
        float4 a6 = w4[(long long)pp[i + 6] * 8 + sub];
        float4 a7 = w4[(long long)pp[i + 7] * 8 + sub];
        acc.x += ((a0.x + a1.x) + (a2.x + a3.x)) + ((a4.x + a5.x) + (a6.x + a7.x));
        acc.y += ((a0.y + a1.y) + (a2.y + a3.y)) + ((a4.y + a5.y) + (a6.y + a7.y));
        acc.z += ((a0.z + a1.z) + (a2.z + a3.z)) + ((a4.z + a5.z) + (a6.z + a7.z));
        acc.w += ((a0.w + a1.w) + (a2.w + a3.w)) + ((a4.w + a5.w) + (a6.w + a7.w));
    }
    for (; i + 4 <= cnt; i += 4) {
        float4 a0 = w4[(long long)pp[i + 0] * 8 + sub];
        float4 a1 = w4[(long long)pp[i + 1] * 8 + sub];
        float4 a2 = w4[(long long)pp[i + 2] * 8 + sub];
        float4 a3 = w4[(long long)pp[i + 3] * 8 + sub];
        acc.x += (a0.x + a1.x) + (a2.x + a3.x);
        acc.y += (a0.y + a1.y) + (a2.y + a3.y);
        acc.z += (a0.z + a1.z) + (a2.z + a3.z);
        acc.w += (a0.w + a1.w) + (a2.w + a3.w);
    }
    for (; i < cnt; ++i) {
        float4 a = w4[(long long)pp[i] * 8 + sub];
        acc.x += a.x; acc.y += a.y; acc.z += a.z; acc.w += a.w;
    }
    out4[(long long)node * 8 + sub] = acc;
}

// Correctness guard: add contributions of overflow edges (degree > PAD). No-op
// for the expected input (ovf[0] == 0).
__global__ __launch_bounds__(256) void overflow_scatter_kernel(const int* __restrict__ src,
                                                               const float4* __restrict__ w4,
                                                               const int* __restrict__ ovf,
                                                               float* __restrict__ out) {
    int n = ovf[0]; if (n > OVF_CAP) n = OVF_CAP;
    long long total = (long long)n * 8;
    int stride = gridDim.x * 256;
    for (long long t = blockIdx.x * 256 + threadIdx.x; t < total; t += stride) {
        int e = ovf[1 + (int)(t >> 3)];
        int sub = (int)(t & 7);
        float4 v = w4[(long long)e * 8 + sub];
        float* o = out + (long long)src[e] * 32 + sub * 4;
        unsafeAtomicAdd(o + 0, v.x);
        unsafeAtomicAdd(o + 1, v.y);
        unsafeAtomicAdd(o + 2, v.z);
        unsafeAtomicAdd(o + 3, v.w);
    }
}

// ---- fallback: direct atomic scatter (F != 32 or tiny ws) ----
__global__ __launch_bounds__(256) void zero_out_kernel(float* __restrict__ out, int n) {
    int i = blockIdx.x * 256 + threadIdx.x;
    if (i < n) out[i] = 0.0f;
}

__global__ __launch_bounds__(256) void scatter_add_generic_kernel(
    const int* __restrict__ src, const float* __restrict__ w,
    float* __restrict__ out, long long total, int F) {
    long long tid = (long long)blockIdx.x * 256 + threadIdx.x;
    if (tid >= total) return;
    int e = (int)(tid / F);
    int f = (int)(tid % F);
    unsafeAtomicAdd(out + (long long)src[e] * F + f, w[tid]);
}

extern "C" void kernel_launch(void* const* d_in, const int* in_sizes, int n_in,
                              void* d_out, int out_size, void* d_ws, size_t ws_size,
                              hipStream_t stream) {
    const int* edge = (const int*)d_in[0];    // [2, E]; first E = src
    const float* w  = (const float*)d_in[1];  // [E, F]
    float* out      = (float*)d_out;          // [N1, F]

    const int E  = in_sizes[0] / 2;
    const int F  = in_sizes[1] / E;
    const int N1 = out_size / F;
    const int* src = edge;
    const int rsize = (N1 + NR - 1) / NR;

    // ws layout: counts[N1] | ovf[1+OVF_CAP] | perm_pad[N1*PAD]
    size_t need = ((size_t)N1 + 1 + OVF_CAP + (size_t)N1 * PAD) * sizeof(int);

    if (F == 32 && ws_size >= need) {
        int* counts   = (int*)d_ws;
        int* ovf      = counts + N1;
        int* perm_pad = ovf + 1 + OVF_CAP;

        zero_kernel<<<(N1 + 1 + 255) / 256, 256, 0, stream>>>(counts, N1 + 1); // counts + ovf[0]
        hist_fill_kernel<<<NR * 256, 256, 0, stream>>>(src, counts, perm_pad, ovf, E, N1, rsize);
        gather_sum_kernel<<<(N1 + 31) / 32, 256, 0, stream>>>(
            counts, perm_pad, (const float4*)w, (float4*)out, N1);
        overflow_scatter_kernel<<<64, 256, 0, stream>>>(src, (const float4*)w, ovf, out);
    } else {
        zero_out_kernel<<<(out_size + 255) / 256, 256, 0, stream>>>(out, out_size);
        long long total = (long long)E * F;
        scatter_add_generic_kernel<<<(int)((total + 255) / 256), 256, 0, stream>>>(
            src, w, out, total, F);
    }
}

// Round 6
// 226.492 us; speedup vs baseline: 5.7144x; 1.0269x over previous
//
#include <hip/hip_runtime.h>

// SpecialSpmmFinal: out[n1, f] = sum over edges e with src[e]==n1 of edge_w[e, f]
// N1=100000, E=3.2M, F=32.
//
// R5b pipeline (F==32):
//   1. zero counts + ovf counter
//   2. hist_fill: fused histogram + padded-slot fill, XCD-range-partitioned
//      (range = blockIdx&7 -> counts slice 50KB + perm_pad slice 3.2MB stay in
//      that XCD's L2; R2 measured 61B/store HBM amplification without this).
//   3. gather_sum: SAME range->blockIdx&7 mapping as hist_fill, so perm_pad and
//      counts are read from the L2 that just wrote them, and out writes are
//      XCD-local. edge_w rows (zero reuse, 410MB) are non-temporal loads to
//      avoid evicting the L2-resident metadata; out stored non-temporally.
//      NT builtins need native clang vectors -> f32x4 ext_vector_type, not
//      HIP_vector_type float4 (R5 compile fail).
//   4. overflow_scatter: degree > PAD correctness guard (no-op expected).

#define NR   8     // node ranges == XCDs
#define PAD  64    // padded slots per node (mean degree 32)
#define OVF_CAP 8192
#define GPB  32    // nodes per gather block (256 thr / 8 lanes-per-node)

typedef float f32x4 __attribute__((ext_vector_type(4)));

__global__ __launch_bounds__(256) void zero_kernel(int* __restrict__ p, int n) {
    int i = blockIdx.x * 256 + threadIdx.x;
    if (i < n) p[i] = 0;
}

// Fused histogram + padded fill, node-range partitioned.
__global__ __launch_bounds__(256) void hist_fill_kernel(const int* __restrict__ src,
                                                        int* __restrict__ counts,
                                                        int* __restrict__ perm_pad,
                                                        int* __restrict__ ovf,
                                                        int E, int N1, int rsize) {
    int range = blockIdx.x & (NR - 1);       // consecutive blocks -> different XCDs
    int lo = range * rsize;
    int hi = lo + rsize; if (hi > N1) hi = N1;
    int bid = blockIdx.x >> 3;
    int nblk = gridDim.x >> 3;
    int stride = nblk * 256 * 4;
    for (int e0 = (bid * 256 + threadIdx.x) * 4; e0 < E; e0 += stride) {
        if (e0 + 4 <= E) {
            int4 s4 = *reinterpret_cast<const int4*>(src + e0);
            int ss[4] = {s4.x, s4.y, s4.z, s4.w};
            #pragma unroll
            for (int k = 0; k < 4; ++k) {
                int s = ss[k];
                if (s >= lo && s < hi) {
                    int r = atomicAdd(&counts[s], 1);
                    if (r < PAD) perm_pad[s * PAD + r] = e0 + k;
                    else {
                        int p = atomicAdd(&ovf[0], 1);
                        if (p < OVF_CAP) ovf[1 + p] = e0 + k;
                    }
                }
            }
        } else {
            for (int e = e0; e < E; ++e) {
                int s = src[e];
                if (s >= lo && s < hi) {
                    int r = atomicAdd(&counts[s], 1);
                    if (r < PAD) perm_pad[s * PAD + r] = e;
                    else {
                        int p = atomicAdd(&ovf[0], 1);
                        if (p < OVF_CAP) ovf[1 + p] = e;
                    }
                }
            }
        }
    }
}

// gather-sum (F == 32): 8 lanes per node, lane owns one f32x4 quad of the row.
// Block->node mapping mirrors hist_fill's range partitioning for L2 locality.
__global__ __launch_bounds__(256) void gather_sum_kernel(const int* __restrict__ counts,
                                                         const int* __restrict__ perm_pad,
                                                         const f32x4* __restrict__ w4,
                                                         f32x4* __restrict__ out4,
                                                         int N1, int rsize) {
    int range = blockIdx.x & (NR - 1);       // same XCD as hist_fill's writes
    int bir   = blockIdx.x >> 3;             // block index within range
    int node  = range * rsize + bir * GPB + (threadIdx.x >> 3);
    int hi    = range * rsize + rsize; if (hi > N1) hi = N1;
    if (node >= hi) return;
    int sub = threadIdx.x & 7;
    int cnt = counts[node]; if (cnt > PAD) cnt = PAD;
    const int* pp = perm_pad + node * PAD;
    f32x4 acc = {0.f, 0.f, 0.f, 0.f};
    int i = 0;
    for (; i + 8 <= cnt; i += 8) {           // 8 independent 128B row reads in flight
        f32x4 a0 = __builtin_nontemporal_load(&w4[(long long)pp[i + 0] * 8 + sub]);
        f32x4 a1 = __builtin_nontemporal_load(&w4[(long long)pp[i + 1] * 8 + sub]);
        f32x4 a2 = __builtin_nontemporal_load(&w4[(long long)pp[i + 2] * 8 + sub]);
        f32x4 a3 = __builtin_nontemporal_load(&w4[(long long)pp[i + 3] * 8 + sub]);
        f32x4 a4 = __builtin_nontemporal_load(&w4[(long long)pp[i + 4] * 8 + sub]);
        f32x4 a5 = __builtin_nontemporal_load(&w4[(long long)pp[i + 5] * 8 + sub]);
        f32x4 a6 = __builtin_nontemporal_load(&w4[(long long)pp[i + 6] * 8 + sub]);
        f32x4 a7 = __builtin_nontemporal_load(&w4[(long long)pp[i + 7] * 8 + sub]);
        acc += ((a0 + a1) + (a2 + a3)) + ((a4 + a5) + (a6 + a7));
    }
    for (; i + 4 <= cnt; i += 4) {
        f32x4 a0 = __builtin_nontemporal_load(&w4[(long long)pp[i + 0] * 8 + sub]);
        f32x4 a1 = __builtin_nontemporal_load(&w4[(long long)pp[i + 1] * 8 + sub]);
        f32x4 a2 = __builtin_nontemporal_load(&w4[(long long)pp[i + 2] * 8 + sub]);
        f32x4 a3 = __builtin_nontemporal_load(&w4[(long long)pp[i + 3] * 8 + sub]);
        acc += (a0 + a1) + (a2 + a3);
    }
    for (; i < cnt; ++i) {
        f32x4 a = __builtin_nontemporal_load(&w4[(long long)pp[i] * 8 + sub]);
        acc += a;
    }
    __builtin_nontemporal_store(acc, &out4[(long long)node * 8 + sub]);
}

// Correctness guard: contributions of overflow edges (degree > PAD).
__global__ __launch_bounds__(256) void overflow_scatter_kernel(const int* __restrict__ src,
                                                               const float* __restrict__ w,
                                                               const int* __restrict__ ovf,
                                                               float* __restrict__ out) {
    int n = ovf[0]; if (n > OVF_CAP) n = OVF_CAP;
    long long total = (long long)n * 32;
    int stride = gridDim.x * 256;
    for (long long t = blockIdx.x * 256 + threadIdx.x; t < total; t += stride) {
        int e = ovf[1 + (int)(t >> 5)];
        int f = (int)(t & 31);
        unsafeAtomicAdd(out + (long long)src[e] * 32 + f, w[(long long)e * 32 + f]);
    }
}

// ---- fallback: direct atomic scatter (F != 32 or tiny ws) ----
__global__ __launch_bounds__(256) void zero_out_kernel(float* __restrict__ out, int n) {
    int i = blockIdx.x * 256 + threadIdx.x;
    if (i < n) out[i] = 0.0f;
}

__global__ __launch_bounds__(256) void scatter_add_generic_kernel(
    const int* __restrict__ src, const float* __restrict__ w,
    float* __restrict__ out, long long total, int F) {
    long long tid = (long long)blockIdx.x * 256 + threadIdx.x;
    if (tid >= total) return;
    int e = (int)(tid / F);
    int f = (int)(tid % F);
    unsafeAtomicAdd(out + (long long)src[e] * F + f, w[tid]);
}

extern "C" void kernel_launch(void* const* d_in, const int* in_sizes, int n_in,
                              void* d_out, int out_size, void* d_ws, size_t ws_size,
                              hipStream_t stream) {
    const int* edge = (const int*)d_in[0];    // [2, E]; first E = src
    const float* w  = (const float*)d_in[1];  // [E, F]
    float* out      = (float*)d_out;          // [N1, F]

    const int E  = in_sizes[0] / 2;
    const int F  = in_sizes[1] / E;
    const int N1 = out_size / F;
    const int* src = edge;
    const int rsize = (N1 + NR - 1) / NR;

    // ws layout: counts[N1] | ovf[1+OVF_CAP] | perm_pad[N1*PAD]
    size_t need = ((size_t)N1 + 1 + OVF_CAP + (size_t)N1 * PAD) * sizeof(int);

    if (F == 32 && ws_size >= need) {
        int* counts   = (int*)d_ws;
        int* ovf      = counts + N1;
        int* perm_pad = ovf + 1 + OVF_CAP;

        zero_kernel<<<(N1 + 1 + 255) / 256, 256, 0, stream>>>(counts, N1 + 1);
        hist_fill_kernel<<<NR * 256, 256, 0, stream>>>(src, counts, perm_pad, ovf, E, N1, rsize);
        int nbpr = (rsize + GPB - 1) / GPB;                 // gather blocks per range
        gather_sum_kernel<<<NR * nbpr, 256, 0, stream>>>(
            counts, perm_pad, (const f32x4*)w, (f32x4*)out, N1, rsize);
        overflow_scatter_kernel<<<64, 256, 0, stream>>>(src, w, ovf, out);
    } else {
        zero_out_kernel<<<(out_size + 255) / 256, 256, 0, stream>>>(out, out_size);
        long long total = (long long)E * F;
        scatter_add_generic_kernel<<<(int)((total + 255) / 256), 256, 0, stream>>>(
            src, w, out, total, F);
    }
}